// Round 13
// baseline (206.126 us; speedup 1.0000x reference)
//
#include <hip/hip_runtime.h>
#include <hip/hip_bf16.h>
#include <stdint.h>

typedef unsigned short u16;
typedef __attribute__((ext_vector_type(8))) short bf16x8;
typedef __attribute__((ext_vector_type(4))) short bf16x4;
typedef __attribute__((ext_vector_type(4))) float f32x4;

__device__ __forceinline__ float bf2f(u16 u) {
    union { unsigned int i; float f; } v; v.i = ((unsigned int)u) << 16; return v.f;
}
__device__ __forceinline__ u16 f2bf(float f) {
    union { float f; unsigned int i; } v; v.f = f;
    unsigned int x = v.i;
    return (u16)((x + 0x7fffu + ((x >> 16) & 1u)) >> 16);
}
__device__ __forceinline__ unsigned fbits(float f) {
    union { float f; unsigned int i; } v; v.f = f; return v.i;
}
__device__ __forceinline__ void async16(const void* g, void* lds) {
    __builtin_amdgcn_global_load_lds((const __attribute__((address_space(1))) void*)g,
                                     (__attribute__((address_space(3))) void*)lds,
                                     16, 0, 0);
}

#define QSCALE 0.18033688f  /* 0.125 * log2(e): folded into Q so attn uses bare exp2 */

// ---------------------------------------------------------------------------
// prep: blocks 0..1023 transpose+convert the 4 weights (Wt[n][k]=bf16(W[k][n]));
//       blocks 1024..3071 convert tgt/memory fp32->bf16.
// ---------------------------------------------------------------------------
__global__ __launch_bounds__(256) void prep(
    const float* __restrict__ tgt, const float* __restrict__ mem,
    const float* __restrict__ Wq, const float* __restrict__ Wk,
    const float* __restrict__ Wv, const float* __restrict__ Wo,
    u16* __restrict__ Wt, u16* __restrict__ tgtb, u16* __restrict__ memb)
{
    __shared__ u16 tile[64][65];
    const int id = blockIdx.x;
    const int tid = threadIdx.x;
    if (id < 1024) {
        const int z = id >> 8;
        const float* in = (z == 0) ? Wq : (z == 1) ? Wk : (z == 2) ? Wv : Wo;
        u16* out = Wt + (size_t)z * 1048576;
        const int k0 = (id & 15) * 64, n0 = ((id >> 4) & 15) * 64;
        const int r = tid >> 2, c0 = (tid & 3) << 4;
#pragma unroll
        for (int i = 0; i < 4; ++i) {
            float4 v = *(const float4*)&in[(size_t)(k0 + r) * 1024 + n0 + c0 + i * 4];
            tile[c0 + i * 4 + 0][r] = f2bf(v.x);
            tile[c0 + i * 4 + 1][r] = f2bf(v.y);
            tile[c0 + i * 4 + 2][r] = f2bf(v.z);
            tile[c0 + i * 4 + 3][r] = f2bf(v.w);
        }
        __syncthreads();
#pragma unroll
        for (int i = 0; i < 2; ++i) {
            bf16x8 v;
#pragma unroll
            for (int j = 0; j < 8; ++j) v[j] = (short)tile[r][c0 + i * 8 + j];
            *(bf16x8*)&out[(size_t)(n0 + r) * 1024 + k0 + c0 + i * 8] = v;
        }
    } else {
        size_t i = ((size_t)(id - 1024) * 256 + tid) * 8;
        float4 a0 = *(const float4*)&tgt[i];
        float4 a1 = *(const float4*)&tgt[i + 4];
        float4 b0 = *(const float4*)&mem[i];
        float4 b1 = *(const float4*)&mem[i + 4];
        bf16x8 va, vb;
        va[0] = (short)f2bf(a0.x); va[1] = (short)f2bf(a0.y);
        va[2] = (short)f2bf(a0.z); va[3] = (short)f2bf(a0.w);
        va[4] = (short)f2bf(a1.x); va[5] = (short)f2bf(a1.y);
        va[6] = (short)f2bf(a1.z); va[7] = (short)f2bf(a1.w);
        vb[0] = (short)f2bf(b0.x); vb[1] = (short)f2bf(b0.y);
        vb[2] = (short)f2bf(b0.z); vb[3] = (short)f2bf(b0.w);
        vb[4] = (short)f2bf(b1.x); vb[5] = (short)f2bf(b1.y);
        vb[6] = (short)f2bf(b1.z); vb[7] = (short)f2bf(b1.w);
        *(bf16x8*)&tgtb[i] = va;
        *(bf16x8*)&memb[i] = vb;
    }
}

// ---------------------------------------------------------------------------
// QKV GEMM v7 (R12): z==0: Q, BK=64, 2-deep vmcnt(8). z==1: K+V merged,
// BK=32, 3-deep vmcnt(12). 72KB LDS pool, byte-offset buffer select.
// ---------------------------------------------------------------------------
__global__ __launch_bounds__(256, 2) void gemm_qkv(
    const u16* __restrict__ tgtb, const u16* __restrict__ memb,
    const u16* __restrict__ Wt,
    const float* __restrict__ bq, const float* __restrict__ bk, const float* __restrict__ bv,
    u16* __restrict__ Qb, u16* __restrict__ Kb, u16* __restrict__ Vtb)
{
    __shared__ __align__(16) u16 pool[36864];   // 72 KB, aliased per z
    const int z = blockIdx.z;

    const int tid = threadIdx.x;
    const int wave = tid >> 6, lane = tid & 63;
    const int quad = lane >> 4, l16 = lane & 15;
    const int m0 = blockIdx.x * 128, n0 = blockIdx.y * 128;
    const int wm = (wave & 1) * 64, wn = (wave >> 1) * 64;
    const int x7 = l16 & 7;

    if (z == 0) {
        const u16* A  = tgtb;
        const u16* Bw = Wt;
        f32x4 acc[4][4] = {};

#define QSTAGE(k0, buf)                                                       \
        {                                                                     \
            _Pragma("unroll")                                                 \
            for (int r = 0; r < 4; ++r) {                                     \
                int c = tid + r * 256;                                        \
                int srow = c >> 3;                                            \
                int g = (c & 7) ^ (srow & 7);                                 \
                async16(A + (size_t)(m0 + srow) * 1024 + (k0) + g * 8,        \
                        (char*)pool + (buf) * 32768 + r * 4096 + wave * 1024);\
                async16(Bw + (size_t)(n0 + srow) * 1024 + (k0) + g * 8,       \
                        (char*)pool + (buf) * 32768 + 16384 + r * 4096 + wave * 1024);\
            }                                                                 \
        }

        QSTAGE(0, 0);
        QSTAGE(64, 1);

        for (int it = 0; it < 16; ++it) {
            if (it < 15) { asm volatile("s_waitcnt vmcnt(8)" ::: "memory"); }
            else         { asm volatile("s_waitcnt vmcnt(0)" ::: "memory"); }
            __builtin_amdgcn_sched_barrier(0);
            __builtin_amdgcn_s_barrier();
            __builtin_amdgcn_sched_barrier(0);

            const u16* a = pool + (it & 1) * 16384;
            const u16* b = a + 8192;
            bf16x8 af[2][4], bfr[2][4];
#pragma unroll
            for (int h = 0; h < 2; ++h)
#pragma unroll
                for (int i = 0; i < 4; ++i) {
                    af[h][i]  = *(const bf16x8*)&a[(wm + i * 16 + l16) * 64 + (((h * 4 + quad) ^ x7) * 8)];
                    bfr[h][i] = *(const bf16x8*)&b[(wn + i * 16 + l16) * 64 + (((h * 4 + quad) ^ x7) * 8)];
                }
            asm volatile("s_waitcnt lgkmcnt(0)" ::: "memory");
            __builtin_amdgcn_sched_barrier(0);
            __builtin_amdgcn_s_barrier();
            __builtin_amdgcn_sched_barrier(0);

            if (it < 14) QSTAGE((it + 2) * 64, it & 1);

            __builtin_amdgcn_s_setprio(1);
#pragma unroll
            for (int h = 0; h < 2; ++h)
#pragma unroll
                for (int i = 0; i < 4; ++i)
#pragma unroll
                    for (int j = 0; j < 4; ++j)
                        acc[i][j] = __builtin_amdgcn_mfma_f32_16x16x32_bf16(af[h][i], bfr[h][j], acc[i][j], 0, 0, 0);
            __builtin_amdgcn_s_setprio(0);
        }
#undef QSTAGE

#pragma unroll
        for (int j = 0; j < 4; ++j) {
            int n = n0 + wn + j * 16 + l16;
            float bb = bq[n];
#pragma unroll
            for (int i = 0; i < 4; ++i) {
                int mb = m0 + wm + i * 16 + quad * 4;
#pragma unroll
                for (int r = 0; r < 4; ++r)
                    Qb[(size_t)(mb + r) * 1024 + n] = f2bf((acc[i][j][r] + bb) * QSCALE);
            }
        }
    } else {
        const u16* A  = memb;
        const u16* B0 = Wt + 1048576;   // Wk
        const u16* B1 = Wt + 2097152;   // Wv
        const int sw = (quad ^ ((l16 >> 1) & 3)) << 3;

        f32x4 accK[4][4] = {};
        f32x4 accV[4][4] = {};

#define KVSTAGE(k0, buf)                                                      \
        {                                                                     \
            _Pragma("unroll")                                                 \
            for (int r = 0; r < 2; ++r) {                                     \
                int c = tid + r * 256;                                        \
                int g = (c & 3) ^ ((c >> 3) & 3);                             \
                const u16* gA = A + (size_t)(m0 + (c >> 2)) * 1024 + (k0) + g * 8;\
                async16(gA, (char*)pool + (buf) * 24576 + r * 4096 + wave * 1024);\
                const u16* gB = B0 + (size_t)(n0 + (c >> 2)) * 1024 + (k0) + g * 8;\
                async16(gB, (char*)pool + (buf) * 24576 + 8192 + r * 4096 + wave * 1024);\
                const u16* gV = B1 + (size_t)(n0 + (c >> 2)) * 1024 + (k0) + g * 8;\
                async16(gV, (char*)pool + (buf) * 24576 + 16384 + r * 4096 + wave * 1024);\
            }                                                                 \
        }

        KVSTAGE(0, 0);
        KVSTAGE(32, 1);
        KVSTAGE(64, 2);

        for (int it = 0; it < 32; ++it) {
            if (it < 30)      { asm volatile("s_waitcnt vmcnt(12)" ::: "memory"); }
            else if (it == 30){ asm volatile("s_waitcnt vmcnt(6)"  ::: "memory"); }
            else              { asm volatile("s_waitcnt vmcnt(0)"  ::: "memory"); }
            __builtin_amdgcn_sched_barrier(0);
            __builtin_amdgcn_s_barrier();
            __builtin_amdgcn_sched_barrier(0);

            const int bsel = it % 3;
            const u16* a  = pool + bsel * 12288;
            const u16* b0 = a + 4096;
            const u16* b1 = a + 8192;
            bf16x8 af[4], bfK[4], bfV[4];
#pragma unroll
            for (int i = 0; i < 4; ++i) {
                af[i]  = *(const bf16x8*)&a[(wm + i * 16 + l16) * 32 + sw];
                bfK[i] = *(const bf16x8*)&b0[(wn + i * 16 + l16) * 32 + sw];
                bfV[i] = *(const bf16x8*)&b1[(wn + i * 16 + l16) * 32 + sw];
            }
            asm volatile("s_waitcnt lgkmcnt(0)" ::: "memory");
            __builtin_amdgcn_sched_barrier(0);
            __builtin_amdgcn_s_barrier();
            __builtin_amdgcn_sched_barrier(0);

            if (it < 29) KVSTAGE((it + 3) * 32, (it + 3) % 3);

            __builtin_amdgcn_s_setprio(1);
#pragma unroll
            for (int i = 0; i < 4; ++i)
#pragma unroll
                for (int j = 0; j < 4; ++j)
                    accK[i][j] = __builtin_amdgcn_mfma_f32_16x16x32_bf16(af[i], bfK[j], accK[i][j], 0, 0, 0);
#pragma unroll
            for (int i = 0; i < 4; ++i)
#pragma unroll
                for (int j = 0; j < 4; ++j)
                    accV[i][j] = __builtin_amdgcn_mfma_f32_16x16x32_bf16(af[i], bfV[j], accV[i][j], 0, 0, 0);
            __builtin_amdgcn_s_setprio(0);
        }
#undef KVSTAGE

        // K epilogue: plain bf16 rows
#pragma unroll
        for (int j = 0; j < 4; ++j) {
            int n = n0 + wn + j * 16 + l16;
            float bb = bk[n];
#pragma unroll
            for (int i = 0; i < 4; ++i) {
                int mb = m0 + wm + i * 16 + quad * 4;
#pragma unroll
                for (int r = 0; r < 4; ++r)
                    Kb[(size_t)(mb + r) * 1024 + n] = f2bf(accK[i][j][r] + bb);
            }
        }
        // V epilogue: transposed per-head layout Vt[bh][d][t]
#pragma unroll
        for (int j = 0; j < 4; ++j) {
            int n = n0 + wn + j * 16 + l16;
            float bb = bv[n];
            int d = n & 63;
#pragma unroll
            for (int i = 0; i < 4; ++i) {
                int mb = m0 + wm + i * 16 + quad * 4;
                int bh = (mb >> 11) * 16 + (n >> 6);
                bf16x4 pk;
#pragma unroll
                for (int r = 0; r < 4; ++r) pk[r] = (short)f2bf(accV[i][j][r] + bb);
                *(bf16x4*)&Vtb[(size_t)bh * 131072 + (size_t)d * 2048 + (mb & 2047)] = pk;
            }
        }
    }
}

// ---------------------------------------------------------------------------
// Output GEMM v6 (R12): 64x128 tile, BK=64, 3-deep vmcnt(12), fp32 out.
// ---------------------------------------------------------------------------
__global__ __launch_bounds__(256, 2) void gemm_out(
    const u16* __restrict__ A, const u16* __restrict__ Bt,
    const float* __restrict__ bias, float* __restrict__ C)
{
    __shared__ __align__(16) u16 sA[3][64 * 64];    // 3 x 8 KB
    __shared__ __align__(16) u16 sB[3][128 * 64];   // 3 x 16 KB
    const int tid = threadIdx.x;
    const int wave = tid >> 6, lane = tid & 63;
    const int quad = lane >> 4, l16 = lane & 15;
    const int m0 = blockIdx.x * 64, n0 = blockIdx.y * 128;
    const int wm = (wave & 1) * 32, wn = (wave >> 1) * 64;
    const int x7 = l16 & 7;
    f32x4 acc[2][4] = {};

#define OSTAGE(k0, buf)                                                       \
    {                                                                         \
        _Pragma("unroll")                                                     \
        for (int r = 0; r < 2; ++r) {                                         \
            int c = tid + r * 256;                                            \
            int srow = c >> 3;                                                \
            int g = (c & 7) ^ (srow & 7);                                     \
            async16(A + (size_t)(m0 + srow) * 1024 + (k0) + g * 8,            \
                    (char*)&sA[buf][0] + r * 4096 + wave * 1024);             \
        }                                                                     \
        _Pragma("unroll")                                                     \
        for (int r = 0; r < 4; ++r) {                                         \
            int c = tid + r * 256;                                            \
            int srow = c >> 3;                                                \
            int g = (c & 7) ^ (srow & 7);                                     \
            async16(Bt + (size_t)(n0 + srow) * 1024 + (k0) + g * 8,           \
                    (char*)&sB[buf][0] + r * 4096 + wave * 1024);             \
        }                                                                     \
    }

    OSTAGE(0, 0);
    OSTAGE(64, 1);
    OSTAGE(128, 2);

    for (int it = 0; it < 16; ++it) {
        if (it < 14)      { asm volatile("s_waitcnt vmcnt(12)" ::: "memory"); }
        else if (it == 14){ asm volatile("s_waitcnt vmcnt(6)"  ::: "memory"); }
        else              { asm volatile("s_waitcnt vmcnt(0)"  ::: "memory"); }
        __builtin_amdgcn_sched_barrier(0);
        __builtin_amdgcn_s_barrier();
        __builtin_amdgcn_sched_barrier(0);

        const int bsel = it % 3;
        const u16* a   = &sA[bsel][0];
        const u16* bb_ = &sB[bsel][0];
        bf16x8 af[2][2], bfr[2][4];
#pragma unroll
        for (int h = 0; h < 2; ++h) {
#pragma unroll
            for (int i = 0; i < 2; ++i)
                af[h][i] = *(const bf16x8*)&a[(wm + i * 16 + l16) * 64 + (((h * 4 + quad) ^ x7) * 8)];
#pragma unroll
            for (int j = 0; j < 4; ++j)
                bfr[h][j] = *(const bf16x8*)&bb_[(wn + j * 16 + l16) * 64 + (((h * 4 + quad) ^ x7) * 8)];
        }
        asm volatile("s_waitcnt lgkmcnt(0)" ::: "memory");
        __builtin_amdgcn_sched_barrier(0);
        __builtin_amdgcn_s_barrier();
        __builtin_amdgcn_sched_barrier(0);

        if (it < 13) OSTAGE((it + 3) * 64, (it + 3) % 3);

        __builtin_amdgcn_s_setprio(1);
#pragma unroll
        for (int h = 0; h < 2; ++h)
#pragma unroll
            for (int i = 0; i < 2; ++i)
#pragma unroll
                for (int j = 0; j < 4; ++j)
                    acc[i][j] = __builtin_amdgcn_mfma_f32_16x16x32_bf16(af[h][i], bfr[h][j], acc[i][j], 0, 0, 0);
        __builtin_amdgcn_s_setprio(0);
    }
#undef OSTAGE

#pragma unroll
    for (int j = 0; j < 4; ++j) {
        int n = n0 + wn + j * 16 + l16;
        float bb = bias[n];
#pragma unroll
        for (int i = 0; i < 2; ++i) {
            int mb = m0 + wm + i * 16 + quad * 4;
#pragma unroll
            for (int r = 0; r < 4; ++r)
                C[(size_t)(mb + r) * 1024 + n] = acc[i][j][r] + bb;
        }
    }
}

// ---------------------------------------------------------------------------
// Attention v10: KVBLK=128 (R8's proven "more MFMA per barrier-pair" lever
// applied to attn). 16 barrier-pairs x 96 MFMA/wave (was 32 x 48). K-tile
// [128kv x 64d] = 16KB (row stride 128B, koff unchanged, ks extends 0..7);
// V-tile [64d x 128kv] = 16KB (row stride 256B -> 16-chunk swizzle:
// stage g=(c&15)^(srow&15), read chunk'=(ks*2+(quad>>1))^l16). LDS 64KB
// dbuf; 2-deep counted-vmcnt(8) pipeline (8 async16/thread/stage).
// ---------------------------------------------------------------------------
__global__ __launch_bounds__(256, 2) void attn_kernel(
    const u16* __restrict__ Q,   // (B*T) x 1024, pre-scaled by QSCALE
    const u16* __restrict__ K,   // (B*T) x 1024
    const u16* __restrict__ Vt,  // (B*H) x 64 x 2048
    u16* __restrict__ Y)         // (B*T) x 1024
{
    __shared__ __align__(16) u16 sK[2][8192];   // [buf][128kv x 64d swizzled]
    __shared__ __align__(16) u16 sV[2][8192];   // [buf][64d x 128kv swizzled]

    const int tid = threadIdx.x;
    const int wave = tid >> 6, lane = tid & 63;
    const int quad = lane >> 4, l16 = lane & 15;

    const int bidx = blockIdx.x;
    const int bh = (bidx & 7) * 4 + ((bidx >> 3) & 3);   // XCD swizzle
    const int qt = bidx >> 5;            // 0..15 (128-q tiles)
    const int b = bh >> 4, h = bh & 15;
    const size_t qrow0 = (size_t)b * 2048 + qt * 128;
    const int st = ((qt << 1) | (bh & 1)) & 15;          // kv stagger (16 tiles)

    const size_t qrowA = qrow0 + wave * 32 + l16;
    const size_t qrowB = qrowA + 16;
    bf16x8 qA0 = *(const bf16x8*)&Q[qrowA * 1024 + h * 64 + quad * 8];
    bf16x8 qA1 = *(const bf16x8*)&Q[qrowA * 1024 + h * 64 + 32 + quad * 8];
    bf16x8 qB0 = *(const bf16x8*)&Q[qrowB * 1024 + h * 64 + quad * 8];
    bf16x8 qB1 = *(const bf16x8*)&Q[qrowB * 1024 + h * 64 + 32 + quad * 8];

    f32x4 oA[4] = {}, oB[4] = {};   // O^T [d=mt*16+quad*4+r][q=l16]
    float rowA = 0.0f, rowB = 0.0f;

    const u16* Kbase = K + (size_t)b * 2048 * 1024 + h * 64;
    const u16* Vbase = Vt + (size_t)bh * 131072;

    const int x7 = l16 & 7;
    // K read offsets (u16): row = ks*16 + l16 (stride 64 u16), chunk
    // (kf*4+quad)^x7 -> koff + ks*1024 at use (ks*16 rows x 64 u16).
    int koff[2];
#pragma unroll
    for (int kf = 0; kf < 2; ++kf)
        koff[kf] = (l16 * 8 + ((kf * 4 + quad) ^ x7)) * 8;
    // V read offsets (u16): row d = mt*16+l16 (stride 128 u16 = 256B),
    // LDS chunk = (ks*2+(quad>>1)) ^ l16 (16-chunk domain), +(quad&1)*4.
    int voff[8];
#pragma unroll
    for (int ks = 0; ks < 8; ++ks)
        voff[ks] = l16 * 128 + (((ks * 2 + (quad >> 1)) ^ l16) * 8) + (quad & 1) * 4;

    // staging: 128kv tile = 16KB K + 16KB V; 8 async16/thread/stage.
#define STAGE1K(kv0, buf, r)                                                  \
    {                                                                         \
        int c = tid + (r) * 256;                                              \
        int srow = c >> 3;                                                    \
        int g = (c & 7) ^ (srow & 7);                                         \
        async16(Kbase + (size_t)((kv0) + srow) * 1024 + g * 8,                \
                (char*)&sK[buf][0] + (r) * 4096 + wave * 1024);               \
    }
#define STAGE1V(kv0, buf, r)                                                  \
    {                                                                         \
        int c = tid + (r) * 256;                                              \
        int srow = c >> 4;                                                    \
        int g = (c & 15) ^ (srow & 15);                                       \
        async16(Vbase + (size_t)srow * 2048 + (kv0) + g * 8,                  \
                (char*)&sV[buf][0] + (r) * 4096 + wave * 1024);               \
    }
#define STAGE(kv0, buf)                                                       \
    STAGE1K(kv0, buf, 0) STAGE1K(kv0, buf, 1) STAGE1K(kv0, buf, 2) STAGE1K(kv0, buf, 3) \
    STAGE1V(kv0, buf, 0) STAGE1V(kv0, buf, 1) STAGE1V(kv0, buf, 2) STAGE1V(kv0, buf, 3)

    STAGE((st & 15) * 128, 0);
    STAGE(((st + 1) & 15) * 128, 1);

    for (int i = 0; i < 16; ++i) {
        // my stage(i) landed; stage(i+1)'s 8 loads may stay in flight
        if (i < 15) { asm volatile("s_waitcnt vmcnt(8)" ::: "memory"); }
        else        { asm volatile("s_waitcnt vmcnt(0)" ::: "memory"); }
        __builtin_amdgcn_sched_barrier(0);
        __builtin_amdgcn_s_barrier();      // all waves: tile(i) fully in LDS
        __builtin_amdgcn_sched_barrier(0);

        const u16* kb = &sK[i & 1][0];
        const u16* vb = &sV[i & 1][0];

        bf16x8 kfr[8][2];
        bf16x4 vfr[4][8];   // [mt][ks]
#pragma unroll
        for (int ks = 0; ks < 8; ++ks) {
            kfr[ks][0] = *(const bf16x8*)&kb[ks * 1024 + koff[0]];
            kfr[ks][1] = *(const bf16x8*)&kb[ks * 1024 + koff[1]];
        }
#pragma unroll
        for (int mt = 0; mt < 4; ++mt)
#pragma unroll
            for (int ks = 0; ks < 8; ++ks)
                vfr[mt][ks] = *(const bf16x4*)&vb[mt * 2048 + voff[ks]];

        asm volatile("s_waitcnt lgkmcnt(0)" ::: "memory");
        __builtin_amdgcn_sched_barrier(0);
        __builtin_amdgcn_s_barrier();      // all waves done reading buf[i&1]
        __builtin_amdgcn_sched_barrier(0);

        if (i < 14) {
            int kvn = ((st + i + 2) & 15) * 128;
            STAGE(kvn, i & 1);             // refill just-freed buffer
        }

        __builtin_amdgcn_s_setprio(1);
#pragma unroll
        for (int ks = 0; ks < 8; ++ks) {
            f32x4 sA = {0.f, 0.f, 0.f, 0.f};
            f32x4 sB = {0.f, 0.f, 0.f, 0.f};
            sA = __builtin_amdgcn_mfma_f32_16x16x32_bf16(kfr[ks][0], qA0, sA, 0, 0, 0);
            sB = __builtin_amdgcn_mfma_f32_16x16x32_bf16(kfr[ks][0], qB0, sB, 0, 0, 0);
            sA = __builtin_amdgcn_mfma_f32_16x16x32_bf16(kfr[ks][1], qA1, sA, 0, 0, 0);
            sB = __builtin_amdgcn_mfma_f32_16x16x32_bf16(kfr[ks][1], qB1, sB, 0, 0, 0);
            float a0 = __builtin_amdgcn_exp2f(sA[0]);
            float a1 = __builtin_amdgcn_exp2f(sA[1]);
            float a2 = __builtin_amdgcn_exp2f(sA[2]);
            float a3 = __builtin_amdgcn_exp2f(sA[3]);
            float b0 = __builtin_amdgcn_exp2f(sB[0]);
            float b1 = __builtin_amdgcn_exp2f(sB[1]);
            float b2 = __builtin_amdgcn_exp2f(sB[2]);
            float b3 = __builtin_amdgcn_exp2f(sB[3]);
            rowA += (a0 + a1) + (a2 + a3);
            rowB += (b0 + b1) + (b2 + b3);
            unsigned loA = __builtin_amdgcn_perm(fbits(a1) + 0x8000u, fbits(a0) + 0x8000u, 0x07060302u);
            unsigned hiA = __builtin_amdgcn_perm(fbits(a3) + 0x8000u, fbits(a2) + 0x8000u, 0x07060302u);
            unsigned loB = __builtin_amdgcn_perm(fbits(b1) + 0x8000u, fbits(b0) + 0x8000u, 0x07060302u);
            unsigned hiB = __builtin_amdgcn_perm(fbits(b3) + 0x8000u, fbits(b2) + 0x8000u, 0x07060302u);
            union { unsigned u[2]; bf16x4 v; } pA, pB;
            pA.u[0] = loA; pA.u[1] = hiA;
            pB.u[0] = loB; pB.u[1] = hiB;
#pragma unroll
            for (int mt = 0; mt < 4; ++mt) {
                oA[mt] = __builtin_amdgcn_mfma_f32_16x16x16bf16_1k(vfr[mt][ks], pA.v, oA[mt], 0, 0, 0);
                oB[mt] = __builtin_amdgcn_mfma_f32_16x16x16bf16_1k(vfr[mt][ks], pB.v, oB[mt], 0, 0, 0);
            }
        }
        __builtin_amdgcn_s_setprio(0);
    }
#undef STAGE
#undef STAGE1K
#undef STAGE1V

    rowA += __shfl_xor(rowA, 16, 64);
    rowA += __shfl_xor(rowA, 32, 64);
    rowB += __shfl_xor(rowB, 16, 64);
    rowB += __shfl_xor(rowB, 32, 64);
    const float invA = 1.0f / rowA;
    const float invB = 1.0f / rowB;

#pragma unroll
    for (int mt = 0; mt < 4; ++mt) {
        bf16x4 oa, ob;
#pragma unroll
        for (int r = 0; r < 4; ++r) {
            oa[r] = (short)f2bf(oA[mt][r] * invA);
            ob[r] = (short)f2bf(oB[mt][r] * invB);
        }
        *(bf16x4*)&Y[qrowA * 1024 + h * 64 + mt * 16 + quad * 4] = oa;
        *(bf16x4*)&Y[qrowB * 1024 + h * 64 + mt * 16 + quad * 4] = ob;
    }
}

// ---------------------------------------------------------------------------
extern "C" void kernel_launch(void* const* d_in, const int* in_sizes, int n_in,
                              void* d_out, int out_size, void* d_ws, size_t ws_size,
                              hipStream_t stream) {
    const float* tgt = (const float*)d_in[0];
    const float* mem = (const float*)d_in[1];
    const float* Wq  = (const float*)d_in[2];
    const float* bq  = (const float*)d_in[3];
    const float* Wk  = (const float*)d_in[4];
    const float* bk  = (const float*)d_in[5];
    const float* Wv  = (const float*)d_in[6];
    const float* bv  = (const float*)d_in[7];
    const float* Wo  = (const float*)d_in[8];
    const float* bo  = (const float*)d_in[9];

    u16* ws = (u16*)d_ws;
    const size_t SZ = 4194304;          // elements per 4096x1024 bf16 buffer
    u16* Wt   = ws;                     // 4 x 1024x1024 bf16 (8 MB)
    u16* tgtb = ws + 4 * SZ;
    u16* memb = tgtb + SZ;
    u16* Qb   = memb + SZ;
    u16* Kb   = Qb + SZ;
    u16* Vtb  = Kb + SZ;                // 32 x 64 x 2048
    u16* Yb   = Vtb + SZ;
    float* out = (float*)d_out;

    prep<<<dim3(3072), 256, 0, stream>>>(tgt, mem, Wq, Wk, Wv, Wo, Wt, tgtb, memb);
    gemm_qkv<<<dim3(32, 8, 2), 256, 0, stream>>>(tgtb, memb, Wt, bq, bk, bv, Qb, Kb, Vtb);
    attn_kernel<<<dim3(512), 256, 0, stream>>>(Qb, Kb, Vtb, Yb);
    gemm_out<<<dim3(64, 8), 256, 0, stream>>>(Yb, Wt + 3 * (size_t)1048576, bo, out);
}

// Round 14
// 190.787 us; speedup vs baseline: 1.0804x; 1.0804x over previous
//
#include <hip/hip_runtime.h>
#include <hip/hip_bf16.h>
#include <stdint.h>

typedef unsigned short u16;
typedef __attribute__((ext_vector_type(8))) short bf16x8;
typedef __attribute__((ext_vector_type(4))) short bf16x4;
typedef __attribute__((ext_vector_type(4))) float f32x4;

__device__ __forceinline__ float bf2f(u16 u) {
    union { unsigned int i; float f; } v; v.i = ((unsigned int)u) << 16; return v.f;
}
__device__ __forceinline__ u16 f2bf(float f) {
    union { float f; unsigned int i; } v; v.f = f;
    unsigned int x = v.i;
    return (u16)((x + 0x7fffu + ((x >> 16) & 1u)) >> 16);
}
__device__ __forceinline__ unsigned fbits(float f) {
    union { float f; unsigned int i; } v; v.f = f; return v.i;
}
__device__ __forceinline__ void async16(const void* g, void* lds) {
    __builtin_amdgcn_global_load_lds((const __attribute__((address_space(1))) void*)g,
                                     (__attribute__((address_space(3))) void*)lds,
                                     16, 0, 0);
}

#define QSCALE 0.18033688f  /* 0.125 * log2(e): folded into Q so attn uses bare exp2 */

// ---------------------------------------------------------------------------
// prep: blocks 0..1023 transpose+convert the 4 weights (Wt[n][k]=bf16(W[k][n]));
//       blocks 1024..3071 convert tgt/memory fp32->bf16.
// ---------------------------------------------------------------------------
__global__ __launch_bounds__(256) void prep(
    const float* __restrict__ tgt, const float* __restrict__ mem,
    const float* __restrict__ Wq, const float* __restrict__ Wk,
    const float* __restrict__ Wv, const float* __restrict__ Wo,
    u16* __restrict__ Wt, u16* __restrict__ tgtb, u16* __restrict__ memb)
{
    __shared__ u16 tile[64][65];
    const int id = blockIdx.x;
    const int tid = threadIdx.x;
    if (id < 1024) {
        const int z = id >> 8;
        const float* in = (z == 0) ? Wq : (z == 1) ? Wk : (z == 2) ? Wv : Wo;
        u16* out = Wt + (size_t)z * 1048576;
        const int k0 = (id & 15) * 64, n0 = ((id >> 4) & 15) * 64;
        const int r = tid >> 2, c0 = (tid & 3) << 4;
#pragma unroll
        for (int i = 0; i < 4; ++i) {
            float4 v = *(const float4*)&in[(size_t)(k0 + r) * 1024 + n0 + c0 + i * 4];
            tile[c0 + i * 4 + 0][r] = f2bf(v.x);
            tile[c0 + i * 4 + 1][r] = f2bf(v.y);
            tile[c0 + i * 4 + 2][r] = f2bf(v.z);
            tile[c0 + i * 4 + 3][r] = f2bf(v.w);
        }
        __syncthreads();
#pragma unroll
        for (int i = 0; i < 2; ++i) {
            bf16x8 v;
#pragma unroll
            for (int j = 0; j < 8; ++j) v[j] = (short)tile[r][c0 + i * 8 + j];
            *(bf16x8*)&out[(size_t)(n0 + r) * 1024 + k0 + c0 + i * 8] = v;
        }
    } else {
        size_t i = ((size_t)(id - 1024) * 256 + tid) * 8;
        float4 a0 = *(const float4*)&tgt[i];
        float4 a1 = *(const float4*)&tgt[i + 4];
        float4 b0 = *(const float4*)&mem[i];
        float4 b1 = *(const float4*)&mem[i + 4];
        bf16x8 va, vb;
        va[0] = (short)f2bf(a0.x); va[1] = (short)f2bf(a0.y);
        va[2] = (short)f2bf(a0.z); va[3] = (short)f2bf(a0.w);
        va[4] = (short)f2bf(a1.x); va[5] = (short)f2bf(a1.y);
        va[6] = (short)f2bf(a1.z); va[7] = (short)f2bf(a1.w);
        vb[0] = (short)f2bf(b0.x); vb[1] = (short)f2bf(b0.y);
        vb[2] = (short)f2bf(b0.z); vb[3] = (short)f2bf(b0.w);
        vb[4] = (short)f2bf(b1.x); vb[5] = (short)f2bf(b1.y);
        vb[6] = (short)f2bf(b1.z); vb[7] = (short)f2bf(b1.w);
        *(bf16x8*)&tgtb[i] = va;
        *(bf16x8*)&memb[i] = vb;
    }
}

// ---------------------------------------------------------------------------
// QKV GEMM v6b (R10 proven): z==0: Q, BK=64, 2-deep vmcnt(8); z==1: K+V
// merged from one staged A tile, BK=32, 2-deep vmcnt(6). 64KB LDS pool,
// byte-offset buffer select (no LDS pointer arrays -- R9 lesson).
// ---------------------------------------------------------------------------
__global__ __launch_bounds__(256, 2) void gemm_qkv(
    const u16* __restrict__ tgtb, const u16* __restrict__ memb,
    const u16* __restrict__ Wt,
    const float* __restrict__ bq, const float* __restrict__ bk, const float* __restrict__ bv,
    u16* __restrict__ Qb, u16* __restrict__ Kb, u16* __restrict__ Vtb)
{
    __shared__ __align__(16) u16 pool[32768];   // 64 KB, aliased per z
    const int z = blockIdx.z;

    const int tid = threadIdx.x;
    const int wave = tid >> 6, lane = tid & 63;
    const int quad = lane >> 4, l16 = lane & 15;
    const int m0 = blockIdx.x * 128, n0 = blockIdx.y * 128;
    const int wm = (wave & 1) * 64, wn = (wave >> 1) * 64;
    const int x7 = l16 & 7;

    if (z == 0) {
        // ---- Q path: BK=64, vmcnt(8), 16 iters ----
        const u16* A  = tgtb;
        const u16* Bw = Wt;
        f32x4 acc[4][4] = {};

#define QSTAGE(k0, buf)                                                       \
        {                                                                     \
            _Pragma("unroll")                                                 \
            for (int r = 0; r < 4; ++r) {                                     \
                int c = tid + r * 256;                                        \
                int srow = c >> 3;                                            \
                int g = (c & 7) ^ (srow & 7);                                 \
                async16(A + (size_t)(m0 + srow) * 1024 + (k0) + g * 8,        \
                        (char*)pool + (buf) * 32768 + r * 4096 + wave * 1024);\
                async16(Bw + (size_t)(n0 + srow) * 1024 + (k0) + g * 8,       \
                        (char*)pool + (buf) * 32768 + 16384 + r * 4096 + wave * 1024);\
            }                                                                 \
        }

        QSTAGE(0, 0);
        QSTAGE(64, 1);

        for (int it = 0; it < 16; ++it) {
            if (it < 15) { asm volatile("s_waitcnt vmcnt(8)" ::: "memory"); }
            else         { asm volatile("s_waitcnt vmcnt(0)" ::: "memory"); }
            __builtin_amdgcn_sched_barrier(0);
            __builtin_amdgcn_s_barrier();
            __builtin_amdgcn_sched_barrier(0);

            const u16* a = pool + (it & 1) * 16384;
            const u16* b = a + 8192;
            bf16x8 af[2][4], bfr[2][4];
#pragma unroll
            for (int h = 0; h < 2; ++h)
#pragma unroll
                for (int i = 0; i < 4; ++i) {
                    af[h][i]  = *(const bf16x8*)&a[(wm + i * 16 + l16) * 64 + (((h * 4 + quad) ^ x7) * 8)];
                    bfr[h][i] = *(const bf16x8*)&b[(wn + i * 16 + l16) * 64 + (((h * 4 + quad) ^ x7) * 8)];
                }
            asm volatile("s_waitcnt lgkmcnt(0)" ::: "memory");
            __builtin_amdgcn_sched_barrier(0);
            __builtin_amdgcn_s_barrier();
            __builtin_amdgcn_sched_barrier(0);

            if (it < 14) QSTAGE((it + 2) * 64, it & 1);

            __builtin_amdgcn_s_setprio(1);
#pragma unroll
            for (int h = 0; h < 2; ++h)
#pragma unroll
                for (int i = 0; i < 4; ++i)
#pragma unroll
                    for (int j = 0; j < 4; ++j)
                        acc[i][j] = __builtin_amdgcn_mfma_f32_16x16x32_bf16(af[h][i], bfr[h][j], acc[i][j], 0, 0, 0);
            __builtin_amdgcn_s_setprio(0);
        }
#undef QSTAGE

#pragma unroll
        for (int j = 0; j < 4; ++j) {
            int n = n0 + wn + j * 16 + l16;
            float bb = bq[n];
#pragma unroll
            for (int i = 0; i < 4; ++i) {
                int mb = m0 + wm + i * 16 + quad * 4;
#pragma unroll
                for (int r = 0; r < 4; ++r)
                    Qb[(size_t)(mb + r) * 1024 + n] = f2bf((acc[i][j][r] + bb) * QSCALE);
            }
        }
    } else {
        // ---- K+V path: BK=32, vmcnt(6), 32 iters ----
        const u16* A  = memb;
        const u16* B0 = Wt + 1048576;   // Wk
        const u16* B1 = Wt + 2097152;   // Wv
        const int sw = (quad ^ ((l16 >> 1) & 3)) << 3;

        f32x4 accK[4][4] = {};
        f32x4 accV[4][4] = {};

#define KVSTAGE(k0, buf)                                                      \
        {                                                                     \
            _Pragma("unroll")                                                 \
            for (int r = 0; r < 2; ++r) {                                     \
                int c = tid + r * 256;                                        \
                int g = (c & 3) ^ ((c >> 3) & 3);                             \
                const u16* gA = A + (size_t)(m0 + (c >> 2)) * 1024 + (k0) + g * 8;\
                async16(gA, (char*)pool + (buf) * 24576 + r * 4096 + wave * 1024);\
                const u16* gB = B0 + (size_t)(n0 + (c >> 2)) * 1024 + (k0) + g * 8;\
                async16(gB, (char*)pool + (buf) * 24576 + 8192 + r * 4096 + wave * 1024);\
                const u16* gV = B1 + (size_t)(n0 + (c >> 2)) * 1024 + (k0) + g * 8;\
                async16(gV, (char*)pool + (buf) * 24576 + 16384 + r * 4096 + wave * 1024);\
            }                                                                 \
        }

        KVSTAGE(0, 0);
        KVSTAGE(32, 1);

        for (int it = 0; it < 32; ++it) {
            if (it < 31) { asm volatile("s_waitcnt vmcnt(6)" ::: "memory"); }
            else         { asm volatile("s_waitcnt vmcnt(0)" ::: "memory"); }
            __builtin_amdgcn_sched_barrier(0);
            __builtin_amdgcn_s_barrier();
            __builtin_amdgcn_sched_barrier(0);

            const u16* a  = pool + (it & 1) * 12288;
            const u16* b0 = a + 4096;
            const u16* b1 = a + 8192;
            bf16x8 af[4], bfK[4], bfV[4];
#pragma unroll
            for (int i = 0; i < 4; ++i) {
                af[i]  = *(const bf16x8*)&a[(wm + i * 16 + l16) * 32 + sw];
                bfK[i] = *(const bf16x8*)&b0[(wn + i * 16 + l16) * 32 + sw];
                bfV[i] = *(const bf16x8*)&b1[(wn + i * 16 + l16) * 32 + sw];
            }
            asm volatile("s_waitcnt lgkmcnt(0)" ::: "memory");
            __builtin_amdgcn_sched_barrier(0);
            __builtin_amdgcn_s_barrier();
            __builtin_amdgcn_sched_barrier(0);

            if (it < 30) KVSTAGE((it + 2) * 32, it & 1);

            __builtin_amdgcn_s_setprio(1);
#pragma unroll
            for (int i = 0; i < 4; ++i)
#pragma unroll
                for (int j = 0; j < 4; ++j)
                    accK[i][j] = __builtin_amdgcn_mfma_f32_16x16x32_bf16(af[i], bfK[j], accK[i][j], 0, 0, 0);
#pragma unroll
            for (int i = 0; i < 4; ++i)
#pragma unroll
                for (int j = 0; j < 4; ++j)
                    accV[i][j] = __builtin_amdgcn_mfma_f32_16x16x32_bf16(af[i], bfV[j], accV[i][j], 0, 0, 0);
            __builtin_amdgcn_s_setprio(0);
        }
#undef KVSTAGE

        // K epilogue: plain bf16 rows
#pragma unroll
        for (int j = 0; j < 4; ++j) {
            int n = n0 + wn + j * 16 + l16;
            float bb = bk[n];
#pragma unroll
            for (int i = 0; i < 4; ++i) {
                int mb = m0 + wm + i * 16 + quad * 4;
#pragma unroll
                for (int r = 0; r < 4; ++r)
                    Kb[(size_t)(mb + r) * 1024 + n] = f2bf(accK[i][j][r] + bb);
            }
        }
        // V epilogue: transposed per-head layout Vt[bh][d][t]
#pragma unroll
        for (int j = 0; j < 4; ++j) {
            int n = n0 + wn + j * 16 + l16;
            float bb = bv[n];
            int d = n & 63;
#pragma unroll
            for (int i = 0; i < 4; ++i) {
                int mb = m0 + wm + i * 16 + quad * 4;
                int bh = (mb >> 11) * 16 + (n >> 6);
                bf16x4 pk;
#pragma unroll
                for (int r = 0; r < 4; ++r) pk[r] = (short)f2bf(accV[i][j][r] + bb);
                *(bf16x4*)&Vtb[(size_t)bh * 131072 + (size_t)d * 2048 + (mb & 2047)] = pk;
            }
        }
    }
}

// ---------------------------------------------------------------------------
// Output GEMM v5 (R10 proven): 64x128 tile, BK=64, counted vmcnt(6)
// 2-deep pipeline, 16 barrier-pairs x 16 MFMA/wave, fp32 out.
// ---------------------------------------------------------------------------
__global__ __launch_bounds__(256, 2) void gemm_out(
    const u16* __restrict__ A, const u16* __restrict__ Bt,
    const float* __restrict__ bias, float* __restrict__ C)
{
    __shared__ __align__(16) u16 sA[2][64 * 64];    // 2 x 8 KB
    __shared__ __align__(16) u16 sB[2][128 * 64];   // 2 x 16 KB
    const int tid = threadIdx.x;
    const int wave = tid >> 6, lane = tid & 63;
    const int quad = lane >> 4, l16 = lane & 15;
    const int m0 = blockIdx.x * 64, n0 = blockIdx.y * 128;
    const int wm = (wave & 1) * 32, wn = (wave >> 1) * 64;
    const int x7 = l16 & 7;
    f32x4 acc[2][4] = {};

#define OSTAGE(k0, buf)                                                       \
    {                                                                         \
        _Pragma("unroll")                                                     \
        for (int r = 0; r < 2; ++r) {                                         \
            int c = tid + r * 256;                                            \
            int srow = c >> 3;                                                \
            int g = (c & 7) ^ (srow & 7);                                     \
            async16(A + (size_t)(m0 + srow) * 1024 + (k0) + g * 8,            \
                    (char*)&sA[buf][0] + r * 4096 + wave * 1024);             \
        }                                                                     \
        _Pragma("unroll")                                                     \
        for (int r = 0; r < 4; ++r) {                                         \
            int c = tid + r * 256;                                            \
            int srow = c >> 3;                                                \
            int g = (c & 7) ^ (srow & 7);                                     \
            async16(Bt + (size_t)(n0 + srow) * 1024 + (k0) + g * 8,           \
                    (char*)&sB[buf][0] + r * 4096 + wave * 1024);             \
        }                                                                     \
    }

    OSTAGE(0, 0);
    OSTAGE(64, 1);

    for (int it = 0; it < 16; ++it) {
        if (it < 15) { asm volatile("s_waitcnt vmcnt(6)" ::: "memory"); }
        else         { asm volatile("s_waitcnt vmcnt(0)" ::: "memory"); }
        __builtin_amdgcn_sched_barrier(0);
        __builtin_amdgcn_s_barrier();
        __builtin_amdgcn_sched_barrier(0);

        const u16* a   = &sA[it & 1][0];
        const u16* bb_ = &sB[it & 1][0];
        bf16x8 af[2][2], bfr[2][4];
#pragma unroll
        for (int h = 0; h < 2; ++h) {
#pragma unroll
            for (int i = 0; i < 2; ++i)
                af[h][i] = *(const bf16x8*)&a[(wm + i * 16 + l16) * 64 + (((h * 4 + quad) ^ x7) * 8)];
#pragma unroll
            for (int j = 0; j < 4; ++j)
                bfr[h][j] = *(const bf16x8*)&bb_[(wn + j * 16 + l16) * 64 + (((h * 4 + quad) ^ x7) * 8)];
        }
        asm volatile("s_waitcnt lgkmcnt(0)" ::: "memory");
        __builtin_amdgcn_sched_barrier(0);
        __builtin_amdgcn_s_barrier();
        __builtin_amdgcn_sched_barrier(0);

        if (it < 14) OSTAGE((it + 2) * 64, it & 1);

        __builtin_amdgcn_s_setprio(1);
#pragma unroll
        for (int h = 0; h < 2; ++h)
#pragma unroll
            for (int i = 0; i < 2; ++i)
#pragma unroll
                for (int j = 0; j < 4; ++j)
                    acc[i][j] = __builtin_amdgcn_mfma_f32_16x16x32_bf16(af[h][i], bfr[h][j], acc[i][j], 0, 0, 0);
        __builtin_amdgcn_s_setprio(0);
    }
#undef OSTAGE

#pragma unroll
    for (int j = 0; j < 4; ++j) {
        int n = n0 + wn + j * 16 + l16;
        float bb = bias[n];
#pragma unroll
        for (int i = 0; i < 2; ++i) {
            int mb = m0 + wm + i * 16 + quad * 4;
#pragma unroll
            for (int r = 0; r < 4; ++r)
                C[(size_t)(mb + r) * 1024 + n] = acc[i][j][r] + bb;
        }
    }
}

// ---------------------------------------------------------------------------
// Attention v9 (R11 proven, best per-dispatch 50.9us): R3 per-wave math
// (4 waves x 32 q rows, groups A/B, register-hoisted fragments, fbits+perm
// pack, setprio) + counted-vmcnt 2-deep kv pipeline (raw s_barrier, steady
// vmcnt(4)). KVBLK=64 (128 measured flat, R13). Structurally final: occupancy
// capped at 2 waves/SIMD by q-work (split-KV and 16q/wave both measured
// worse); pipes ~76% co-issued.
// ---------------------------------------------------------------------------
__global__ __launch_bounds__(256, 2) void attn_kernel(
    const u16* __restrict__ Q,   // (B*T) x 1024, pre-scaled by QSCALE
    const u16* __restrict__ K,   // (B*T) x 1024
    const u16* __restrict__ Vt,  // (B*H) x 64 x 2048
    u16* __restrict__ Y)         // (B*T) x 1024
{
    __shared__ __align__(16) u16 sK[2][4096];   // [buf][64kv x 64d swizzled]
    __shared__ __align__(16) u16 sV[2][4096];   // [buf][64d x 64kv swizzled]

    const int tid = threadIdx.x;
    const int wave = tid >> 6, lane = tid & 63;
    const int quad = lane >> 4, l16 = lane & 15;

    const int bidx = blockIdx.x;
    const int bh = (bidx & 7) * 4 + ((bidx >> 3) & 3);   // XCD swizzle
    const int qt = bidx >> 5;            // 0..15 (128-q tiles)
    const int b = bh >> 4, h = bh & 15;
    const size_t qrow0 = (size_t)b * 2048 + qt * 128;
    const int st = ((qt << 1) | (bh & 1)) & 31;          // kv stagger

    const size_t qrowA = qrow0 + wave * 32 + l16;
    const size_t qrowB = qrowA + 16;
    bf16x8 qA0 = *(const bf16x8*)&Q[qrowA * 1024 + h * 64 + quad * 8];
    bf16x8 qA1 = *(const bf16x8*)&Q[qrowA * 1024 + h * 64 + 32 + quad * 8];
    bf16x8 qB0 = *(const bf16x8*)&Q[qrowB * 1024 + h * 64 + quad * 8];
    bf16x8 qB1 = *(const bf16x8*)&Q[qrowB * 1024 + h * 64 + 32 + quad * 8];

    f32x4 oA[4] = {}, oB[4] = {};   // O^T [d=mt*16+quad*4+r][q=l16]
    float rowA = 0.0f, rowB = 0.0f;

    const u16* Kbase = K + (size_t)b * 2048 * 1024 + h * 64;
    const u16* Vbase = Vt + (size_t)bh * 131072;

    const int x7 = l16 & 7;
    int koff[2], voff[4];
#pragma unroll
    for (int kf = 0; kf < 2; ++kf)
        koff[kf] = (l16 * 8 + ((kf * 4 + quad) ^ x7)) * 8;
#pragma unroll
    for (int ks = 0; ks < 4; ++ks)
        voff[ks] = (l16 * 8 + ((ks * 2 + (quad >> 1)) ^ x7)) * 8 + (quad & 1) * 4;

#define STAGE1(kv0, buf, r)                                                   \
    {                                                                         \
        int c = tid + (r) * 256;                                              \
        int srow = c >> 3;                                                    \
        int g = (c & 7) ^ (srow & 7);                                         \
        async16(Kbase + (size_t)((kv0) + srow) * 1024 + g * 8,                \
                (char*)&sK[buf][0] + (r) * 4096 + wave * 1024);               \
        async16(Vbase + (size_t)srow * 2048 + (kv0) + g * 8,                  \
                (char*)&sV[buf][0] + (r) * 4096 + wave * 1024);               \
    }
#define STAGE(kv0, buf) STAGE1(kv0, buf, 0) STAGE1(kv0, buf, 1)

    STAGE((st & 31) * 64, 0);
    STAGE(((st + 1) & 31) * 64, 1);

    for (int i = 0; i < 32; ++i) {
        if (i < 31) { asm volatile("s_waitcnt vmcnt(4)" ::: "memory"); }
        else        { asm volatile("s_waitcnt vmcnt(0)" ::: "memory"); }
        __builtin_amdgcn_sched_barrier(0);
        __builtin_amdgcn_s_barrier();      // all waves: tile(i) fully in LDS
        __builtin_amdgcn_sched_barrier(0);

        const u16* kb = &sK[i & 1][0];
        const u16* vb = &sV[i & 1][0];

        bf16x8 kfr[4][2];
        bf16x4 vfr[4][4];   // [mt][ks]
#pragma unroll
        for (int ks = 0; ks < 4; ++ks) {
            kfr[ks][0] = *(const bf16x8*)&kb[ks * 1024 + koff[0]];
            kfr[ks][1] = *(const bf16x8*)&kb[ks * 1024 + koff[1]];
        }
#pragma unroll
        for (int mt = 0; mt < 4; ++mt)
#pragma unroll
            for (int ks = 0; ks < 4; ++ks)
                vfr[mt][ks] = *(const bf16x4*)&vb[mt * 1024 + voff[ks]];

        asm volatile("s_waitcnt lgkmcnt(0)" ::: "memory");
        __builtin_amdgcn_sched_barrier(0);
        __builtin_amdgcn_s_barrier();      // all waves done reading buf[i&1]
        __builtin_amdgcn_sched_barrier(0);

        if (i < 30) {
            int kvn = ((st + i + 2) & 31) * 64;
            STAGE(kvn, i & 1);             // refill just-freed buffer
        }

        __builtin_amdgcn_s_setprio(1);
#pragma unroll
        for (int ks = 0; ks < 4; ++ks) {
            f32x4 sA = {0.f, 0.f, 0.f, 0.f};
            f32x4 sB = {0.f, 0.f, 0.f, 0.f};
            sA = __builtin_amdgcn_mfma_f32_16x16x32_bf16(kfr[ks][0], qA0, sA, 0, 0, 0);
            sB = __builtin_amdgcn_mfma_f32_16x16x32_bf16(kfr[ks][0], qB0, sB, 0, 0, 0);
            sA = __builtin_amdgcn_mfma_f32_16x16x32_bf16(kfr[ks][1], qA1, sA, 0, 0, 0);
            sB = __builtin_amdgcn_mfma_f32_16x16x32_bf16(kfr[ks][1], qB1, sB, 0, 0, 0);
            float a0 = __builtin_amdgcn_exp2f(sA[0]);
            float a1 = __builtin_amdgcn_exp2f(sA[1]);
            float a2 = __builtin_amdgcn_exp2f(sA[2]);
            float a3 = __builtin_amdgcn_exp2f(sA[3]);
            float b0 = __builtin_amdgcn_exp2f(sB[0]);
            float b1 = __builtin_amdgcn_exp2f(sB[1]);
            float b2 = __builtin_amdgcn_exp2f(sB[2]);
            float b3 = __builtin_amdgcn_exp2f(sB[3]);
            rowA += (a0 + a1) + (a2 + a3);
            rowB += (b0 + b1) + (b2 + b3);
            unsigned loA = __builtin_amdgcn_perm(fbits(a1) + 0x8000u, fbits(a0) + 0x8000u, 0x07060302u);
            unsigned hiA = __builtin_amdgcn_perm(fbits(a3) + 0x8000u, fbits(a2) + 0x8000u, 0x07060302u);
            unsigned loB = __builtin_amdgcn_perm(fbits(b1) + 0x8000u, fbits(b0) + 0x8000u, 0x07060302u);
            unsigned hiB = __builtin_amdgcn_perm(fbits(b3) + 0x8000u, fbits(b2) + 0x8000u, 0x07060302u);
            union { unsigned u[2]; bf16x4 v; } pA, pB;
            pA.u[0] = loA; pA.u[1] = hiA;
            pB.u[0] = loB; pB.u[1] = hiB;
#pragma unroll
            for (int mt = 0; mt < 4; ++mt) {
                oA[mt] = __builtin_amdgcn_mfma_f32_16x16x16bf16_1k(vfr[mt][ks], pA.v, oA[mt], 0, 0, 0);
                oB[mt] = __builtin_amdgcn_mfma_f32_16x16x16bf16_1k(vfr[mt][ks], pB.v, oB[mt], 0, 0, 0);
            }
        }
        __builtin_amdgcn_s_setprio(0);
    }
#undef STAGE
#undef STAGE1

    rowA += __shfl_xor(rowA, 16, 64);
    rowA += __shfl_xor(rowA, 32, 64);
    rowB += __shfl_xor(rowB, 16, 64);
    rowB += __shfl_xor(rowB, 32, 64);
    const float invA = 1.0f / rowA;
    const float invB = 1.0f / rowB;

#pragma unroll
    for (int mt = 0; mt < 4; ++mt) {
        bf16x4 oa, ob;
#pragma unroll
        for (int r = 0; r < 4; ++r) {
            oa[r] = (short)f2bf(oA[mt][r] * invA);
            ob[r] = (short)f2bf(oB[mt][r] * invB);
        }
        *(bf16x4*)&Y[qrowA * 1024 + h * 64 + mt * 16 + quad * 4] = oa;
        *(bf16x4*)&Y[qrowB * 1024 + h * 64 + mt * 16 + quad * 4] = ob;
    }
}

// ---------------------------------------------------------------------------
extern "C" void kernel_launch(void* const* d_in, const int* in_sizes, int n_in,
                              void* d_out, int out_size, void* d_ws, size_t ws_size,
                              hipStream_t stream) {
    const float* tgt = (const float*)d_in[0];
    const float* mem = (const float*)d_in[1];
    const float* Wq  = (const float*)d_in[2];
    const float* bq  = (const float*)d_in[3];
    const float* Wk  = (const float*)d_in[4];
    const float* bk  = (const float*)d_in[5];
    const float* Wv  = (const float*)d_in[6];
    const float* bv  = (const float*)d_in[7];
    const float* Wo  = (const float*)d_in[8];
    const float* bo  = (const float*)d_in[9];

    u16* ws = (u16*)d_ws;
    const size_t SZ = 4194304;          // elements per 4096x1024 bf16 buffer
    u16* Wt   = ws;                     // 4 x 1024x1024 bf16 (8 MB)
    u16* tgtb = ws + 4 * SZ;
    u16* memb = tgtb + SZ;
    u16* Qb   = memb + SZ;
    u16* Kb   = Qb + SZ;
    u16* Vtb  = Kb + SZ;                // 32 x 64 x 2048
    u16* Yb   = Vtb + SZ;
    float* out = (float*)d_out;

    prep<<<dim3(3072), 256, 0, stream>>>(tgt, mem, Wq, Wk, Wv, Wo, Wt, tgtb, memb);
    gemm_qkv<<<dim3(32, 8, 2), 256, 0, stream>>>(tgtb, memb, Wt, bq, bk, bv, Qb, Kb, Vtb);
    attn_kernel<<<dim3(512), 256, 0, stream>>>(Qb, Kb, Vtb, Yb);
    gemm_out<<<dim3(64, 8), 256, 0, stream>>>(Yb, Wt + 3 * (size_t)1048576, bo, out);
}